// Round 14
// baseline (132.484 us; speedup 1.0000x reference)
//
#include <hip/hip_runtime.h>
#include <hip/hip_bf16.h>

// Joiner: logits[n,t,u,v] = sum_d tanh(enc[n,t,d]+dec[n,u,d]) * W[v,d] + b[v]
// N=8 T=200 U=100 D=512 V=500  -> GEMM M=160000, K=512, N=500 (padded 512)
//
// R11 = R10 (130.6us: counted-vmcnt cross-barrier B prefetch) + RAW-BARRIER
// EPILOGUE: __syncthreads() drains vmcnt(0), forcing each epilogue chunk to
// wait for the previous chunk's 2048 global stores to retire. Replace with
// {s_waitcnt lgkmcnt(0); s_barrier} (LDS ordering only) -- stores pipeline
// across chunks, draining once at s_endpgm. Also 32-row chunks (64KB LDS,
// still 2 blocks/CU): half the barriers, longer store bursts.

#define NB 8
#define TT 200
#define UU 100
#define DD 512
#define VV 500
#define VP 512
#define BM 64
#define BK 32
#define KSTEPS 16          // 512/32
#define THREADS 256
#define LDA 40             // BK + 8 pad (ushort units, 80B row stride)
#define MROWS (NB*TT*UU)   // 160000
#define MBLOCKS (MROWS/BM) // 2500

typedef __attribute__((ext_vector_type(4))) float         f32x4;
typedef __attribute__((ext_vector_type(8))) short         s16x8;
typedef __attribute__((ext_vector_type(4))) unsigned int  u32x4;

#define RAW_BAR() do { asm volatile("s_waitcnt lgkmcnt(0)" ::: "memory"); \
                       __builtin_amdgcn_s_barrier(); } while (0)

__device__ __forceinline__ unsigned short f2bf(float f) {
    unsigned int u = __builtin_bit_cast(unsigned int, f);
    u = (u + 0x7FFFu + ((u >> 16) & 1u)) >> 16;   // round-to-nearest-even
    return (unsigned short)u;
}

// pack 2 f32 -> 2 bf16 (RNE) in one instruction
__device__ __forceinline__ unsigned int cvt_pk_bf16(float a, float b) {
    unsigned int r;
    asm("v_cvt_pk_bf16_f32 %0, %1, %2" : "=v"(r) : "v"(a), "v"(b));
    return r;
}

__device__ __forceinline__ float fast_tanh(float x) {
    // tanh(x) = 1 - 2/(1+2^(2x*log2e)); saturations via exp inf/0
    float e = __builtin_amdgcn_exp2f(x * 2.88539008177793f);
    return __builtin_fmaf(-2.0f, __builtin_amdgcn_rcpf(e + 1.0f), 1.0f);
}

// ---- prep: W (500x512 f32) -> bf16, padded to 512 rows, tiled [kc][v][32] ----
__global__ void prep_w(const float* __restrict__ W, unsigned short* __restrict__ Wt) {
    int idx = blockIdx.x * 256 + threadIdx.x;   // 0 .. 512*512-1
    int k = idx & 511;
    int v = idx >> 9;
    float val = (v < VV) ? W[v * DD + k] : 0.0f;
    Wt[(k >> 5) * (VP * BK) + v * BK + (k & 31)] = f2bf(val);
}

// One K-step. At entry: CUR holds A[kc] (barrier passed), BC holds B[kc]
// (loads in flight, counted-vmcnt at consume), e/d regs hold enc/dec[kc+1].
#define KBODY(kc, CUR, NXT, BC, BNX)                                          \
  {                                                                           \
    /* issue next step's B fragments (stay in flight across the barrier) */   \
    if ((kc) < KSTEPS - 1) {                                                  \
      _Pragma("unroll")                                                       \
      for (int f = 0; f < 8; ++f)                                             \
        BNX[f] = *(const s16x8*)(wptr + ((kc)+1) * (VP * BK) + f * (16*BK));  \
    }                                                                         \
    /* A fragments for this step */                                           \
    s16x8 aF[4];                                                              \
    _Pragma("unroll")                                                         \
    for (int m = 0; m < 4; ++m)                                               \
      aF[m] = *(const s16x8*)(&CUR[(m * 16 + lr) * LDA + lk * 8]);            \
    /* stage A[kc+1] from e/d regs, then load e/d for kc+2 */                 \
    if ((kc) < KSTEPS - 1) {                                                  \
      u32x4 wds;                                                              \
      wds[0] = cvt_pk_bf16(fast_tanh(e0[0]+d0[0]), fast_tanh(e0[1]+d0[1]));   \
      wds[1] = cvt_pk_bf16(fast_tanh(e0[2]+d0[2]), fast_tanh(e0[3]+d0[3]));   \
      wds[2] = cvt_pk_bf16(fast_tanh(e1[0]+d1[0]), fast_tanh(e1[1]+d1[1]));   \
      wds[3] = cvt_pk_bf16(fast_tanh(e1[2]+d1[2]), fast_tanh(e1[3]+d1[3]));   \
      *(u32x4*)(&NXT[srow * LDA + sk]) = wds;                                 \
      if ((kc) < KSTEPS - 2) {                                                \
        const float* e2 = ep + ((kc)+2) * BK;                                 \
        const float* d2 = dp + ((kc)+2) * BK;                                 \
        e0 = *(const f32x4*)(e2);  e1 = *(const f32x4*)(e2 + 4);              \
        d0 = *(const f32x4*)(d2);  d1 = *(const f32x4*)(d2 + 4);              \
      }                                                                       \
    }                                                                         \
    /* 32 MFMAs on BC (compiler emits counted vmcnt, not 0) */                \
    __builtin_amdgcn_s_setprio(1);                                            \
    _Pragma("unroll")                                                         \
    for (int m = 0; m < 4; ++m)                                               \
      _Pragma("unroll")                                                       \
      for (int f = 0; f < 8; ++f)                                             \
        acc[m][f] = __builtin_amdgcn_mfma_f32_16x16x32_bf16(aF[m], BC[f],     \
                                                            acc[m][f],0,0,0); \
    __builtin_amdgcn_s_setprio(0);                                            \
    /* raw barrier: drain LDS only, keep global loads in flight */            \
    if ((kc) < KSTEPS - 1) RAW_BAR();                                         \
  }

__global__ __launch_bounds__(THREADS, 2) void joiner_kernel(
    const float* __restrict__ enc, const float* __restrict__ dec,
    const unsigned short* __restrict__ Wt, const float* __restrict__ bias,
    float* __restrict__ out)
{
    // union: K-loop A dbuf (2 x 5120 B) / epilogue chunk 32x500 f32 (64000 B)
    __shared__ __align__(16) char smem[64000];
    unsigned short* lA0 = (unsigned short*)smem;
    unsigned short* lA1 = (unsigned short*)(smem + BM * LDA * 2);

    const int tid  = threadIdx.x;
    const int mb   = blockIdx.x;
    const int lane = tid & 63;
    const int wn   = tid >> 6;       // 0..3: 128-col quarter
    const int lr   = lane & 15;
    const int lk   = lane >> 4;

    // staging: each thread produces 8 activations of one row
    const int srow = tid >> 2;          // 0..63
    const int sk   = (tid & 3) << 3;    // 0,8,16,24

    int r   = mb * BM + srow;
    int n   = r / (TT * UU);
    int rem = r - n * (TT * UU);
    int t   = rem / UU;
    int u   = rem - t * UU;
    const float* ep = enc + (n * TT + t) * DD + sk;
    const float* dp = dec + (n * UU + u) * DD + sk;

    // per-thread B pointer into pre-tiled Wt: v = wn*128 + f*16 + lr, k = lk*8
    const unsigned short* wptr = Wt + (wn * 128 + lr) * BK + lk * 8;

    f32x4 e0, e1, d0, d1;
    s16x8 b0[8], b1[8];

    // ---- prologue: e/d[0], issue B[0], stage A[0], e/d[1], barrier ----
    e0 = *(const f32x4*)(ep);     e1 = *(const f32x4*)(ep + 4);
    d0 = *(const f32x4*)(dp);     d1 = *(const f32x4*)(dp + 4);
    #pragma unroll
    for (int f = 0; f < 8; ++f)
        b0[f] = *(const s16x8*)(wptr + f * (16 * BK));
    {
        u32x4 wds;
        wds[0] = cvt_pk_bf16(fast_tanh(e0[0]+d0[0]), fast_tanh(e0[1]+d0[1]));
        wds[1] = cvt_pk_bf16(fast_tanh(e0[2]+d0[2]), fast_tanh(e0[3]+d0[3]));
        wds[2] = cvt_pk_bf16(fast_tanh(e1[0]+d1[0]), fast_tanh(e1[1]+d1[1]));
        wds[3] = cvt_pk_bf16(fast_tanh(e1[2]+d1[2]), fast_tanh(e1[3]+d1[3]));
        *(u32x4*)(&lA0[srow * LDA + sk]) = wds;
    }
    e0 = *(const f32x4*)(ep + BK);     e1 = *(const f32x4*)(ep + BK + 4);
    d0 = *(const f32x4*)(dp + BK);     d1 = *(const f32x4*)(dp + BK + 4);
    RAW_BAR();

    f32x4 acc[4][8];
    #pragma unroll
    for (int m = 0; m < 4; ++m)
        #pragma unroll
        for (int f = 0; f < 8; ++f)
            acc[m][f] = (f32x4){0.f, 0.f, 0.f, 0.f};

    // ---- K-loop: 8 x 2 bodies; B reg-dbuf b0/b1, A LDS-dbuf lA0/lA1 ----
    #pragma unroll
    for (int kk = 0; kk < KSTEPS; kk += 2) {
        KBODY(kk,     lA0, lA1, b0, b1)
        KBODY(kk + 1, lA1, lA0, b1, b0)
    }

    // ---- epilogue: acc -> LDS 32-row chunks -> streaming f32x4 stores ----
    // Raw (lgkm-only) barriers: stores stay in flight across chunks.
    float bv[8];
    #pragma unroll
    for (int f = 0; f < 8; ++f) {
        int v = wn * 128 + f * 16 + lr;
        bv[f] = (v < VV) ? bias[v] : 0.0f;
    }

    float* lchunk = (float*)smem;                 // 32*500 f32 = 64000 B
    float* outbase = out + (long)mb * BM * VV;

    #pragma unroll
    for (int c = 0; c < 2; ++c) {
        RAW_BAR();   // previous chunk's ds_reads done; K-loop LDS free
        #pragma unroll
        for (int mm = 0; mm < 2; ++mm) {
            int m = c * 2 + mm;
            #pragma unroll
            for (int f = 0; f < 8; ++f) {
                int v = wn * 128 + f * 16 + lr;
                if (v < VV) {
                    #pragma unroll
                    for (int q = 0; q < 4; ++q)
                        lchunk[(mm * 16 + lk * 4 + q) * VV + v] = acc[m][f][q] + bv[f];
                }
            }
        }
        RAW_BAR();   // chunk writes visible
        // 32 rows x 500 f32 = 16000 contiguous floats = 4000 f32x4
        float* dst = outbase + c * 32 * VV;
        #pragma unroll
        for (int i = 0; i < 16; ++i) {
            int c4 = i * THREADS + tid;        // 0..4095
            if (c4 < 4000)
                *(f32x4*)(dst + c4 * 4) = *(const f32x4*)(lchunk + c4 * 4);
        }
    }
}

extern "C" void kernel_launch(void* const* d_in, const int* in_sizes, int n_in,
                              void* d_out, int out_size, void* d_ws, size_t ws_size,
                              hipStream_t stream) {
    const float* enc = (const float*)d_in[0];
    const float* dec = (const float*)d_in[1];
    const float* W   = (const float*)d_in[2];
    const float* b   = (const float*)d_in[3];
    float* out = (float*)d_out;
    unsigned short* Wt = (unsigned short*)d_ws;   // 512*512*2 = 512 KB

    prep_w<<<dim3((VP * DD) / 256), dim3(256), 0, stream>>>(W, Wt);
    joiner_kernel<<<dim3(MBLOCKS), dim3(THREADS), 0, stream>>>(enc, dec, Wt, b, out);
}